// Round 6
// baseline (377.017 us; speedup 1.0000x reference)
//
#include <hip/hip_runtime.h>
#include <cstddef>
#include <cstdint>

#define B_ 4
#define S_ 1024
#define E_ 512
#define H_ 8
#define F_ 2048
// DK=64, scale=1/8; token pitch of fused qkv buffer:
#define QKV_P 1024

typedef __attribute__((ext_vector_type(8))) short s16x8;
typedef __attribute__((ext_vector_type(4))) short s16x4;
typedef __attribute__((ext_vector_type(4))) float f32x4;

static __device__ __forceinline__ short f2bf(float f) {
  union { float f; unsigned u; } x; x.f = f;
  unsigned r = x.u + 0x7fffu + ((x.u >> 16) & 1u);   // RNE
  return (short)(r >> 16);
}

static __device__ __forceinline__ void gload_lds16(const void* g, void* l) {
  __builtin_amdgcn_global_load_lds(
      (const __attribute__((address_space(1))) void*)g,
      (__attribute__((address_space(3))) void*)l, 16, 0, 0);
}

// ---------------------------------------------------------------------------
// x fp32 -> bf16
// ---------------------------------------------------------------------------
__global__ __launch_bounds__(256) void f2b_kernel(const float* __restrict__ in,
                                                  short* __restrict__ out, int n) {
  int i = (blockIdx.x * 256 + threadIdx.x) * 4;
  if (i >= n) return;
  const float4 v = *(const float4*)&in[i];
  s16x4 o = { f2bf(v.x), f2bf(v.y), f2bf(v.z), f2bf(v.w) };
  *(s16x4*)&out[i] = o;
}

// ---------------------------------------------------------------------------
// One dispatch: all 5 weight transposes (fp32 [K][N] -> bf16 [N][K]) + bias
// concat bqv = [bq|bv].
// ---------------------------------------------------------------------------
__global__ __launch_bounds__(256) void prep_weights_kernel(
    const float* __restrict__ Wq, const float* __restrict__ Wv,
    const float* __restrict__ Wo, const float* __restrict__ W1,
    const float* __restrict__ W2, const float* __restrict__ bq,
    const float* __restrict__ bv, short* __restrict__ WqvT,
    short* __restrict__ WoT, short* __restrict__ W1T, short* __restrict__ W2T,
    float* __restrict__ bqv)
{
  const int bid = blockIdx.x;
  const float* src; short* dst; int K, N, lb;
  if (bid < 256)       { src = Wq; dst = WqvT;             K = 512;  N = 512;  lb = bid; }
  else if (bid < 512)  { src = Wv; dst = WqvT + 512 * 512; K = 512;  N = 512;  lb = bid - 256; }
  else if (bid < 768)  { src = Wo; dst = WoT;              K = 512;  N = 512;  lb = bid - 512; }
  else if (bid < 1792) { src = W1; dst = W1T;              K = 512;  N = 2048; lb = bid - 768; }
  else if (bid < 2816) { src = W2; dst = W2T;              K = 2048; N = 512;  lb = bid - 1792; }
  else {
    const int i = threadIdx.x * 4;
    float4 v = (i < 512) ? *(const float4*)&bq[i] : *(const float4*)&bv[i - 512];
    *(float4*)&bqv[i] = v;
    return;
  }
  const int nbx = N / 32;
  const int bx = (lb % nbx) * 32, by = (lb / nbx) * 32;
  __shared__ float tile[32][33];
  const int tx = threadIdx.x & 31, ty = threadIdx.x >> 5;
  #pragma unroll
  for (int i = ty; i < 32; i += 8)
    tile[i][tx] = src[(size_t)(by + i) * N + bx + tx];
  __syncthreads();
  #pragma unroll
  for (int i = ty; i < 32; i += 8)
    dst[(size_t)(bx + i) * K + by + tx] = f2bf(tile[tx][i]);
}

// ---------------------------------------------------------------------------
// kv head-transpose: VT[(b*H+h)*64 + d][s] = QKV[(b*S+s)*QKV_P + 512 + h*64 + d]
// ---------------------------------------------------------------------------
__global__ __launch_bounds__(256) void vtrans_kernel(const short* __restrict__ QKV,
                                                     short* __restrict__ VT)
{
  __shared__ short tile[32][33];
  const int s0 = blockIdx.x * 32;
  const int d0 = blockIdx.y * 32;
  const int bh = blockIdx.z;             // b*H + h
  const int b = bh >> 3, h = bh & 7;
  const int tx = threadIdx.x & 31, ty = threadIdx.x >> 5;   // 32 x 8
  #pragma unroll
  for (int i = ty; i < 32; i += 8)
    tile[i][tx] = QKV[(size_t)(b * S_ + s0 + i) * QKV_P + 512 + h * 64 + d0 + tx];
  __syncthreads();
  #pragma unroll
  for (int i = ty; i < 32; i += 8)
    VT[(size_t)(bh * 64 + d0 + i) * S_ + s0 + tx] = tile[tx][i];
}

// ---------------------------------------------------------------------------
// MFMA GEMM, tile BMxBN (m97 structure), BK=32, 256 thr = 4 waves (2x2).
// ---------------------------------------------------------------------------
template<int BM, int BN, int ACT, int OUTF>
__global__ __launch_bounds__(256) void gemm_t(
    const short* __restrict__ A, const short* __restrict__ Bt,
    const float* __restrict__ bias, float* __restrict__ Cf,
    short* __restrict__ Cb, int M, int N, int K)
{
  constexpr int MR = BM / 32;
  constexpr int NR = BN / 32;
  __shared__ __align__(16) short As[BM * 32];
  __shared__ __align__(16) short Bs[BN * 32];

  const int t = threadIdx.x;
  const int w = t >> 6, lane = t & 63;
  const int wr = w >> 1, wc = w & 1;
  const int lr = lane & 15, lg = lane >> 4;
  const int bm = blockIdx.y * BM, bn = blockIdx.x * BN;
  const int srow = t >> 2, skcol = (t & 3) * 8;

  f32x4 acc[MR][NR] = {};

  for (int k0 = 0; k0 < K; k0 += 32) {
    #pragma unroll
    for (int i = 0; i < BM / 64; ++i)
      gload_lds16(&A[(size_t)(bm + i * 64 + srow) * K + k0 + skcol], &As[i * 2048 + t * 8]);
    #pragma unroll
    for (int i = 0; i < BN / 64; ++i)
      gload_lds16(&Bt[(size_t)(bn + i * 64 + srow) * K + k0 + skcol], &Bs[i * 2048 + t * 8]);
    __syncthreads();

    s16x8 af[MR], bf[NR];
    #pragma unroll
    for (int m = 0; m < MR; ++m)
      af[m] = *(const s16x8*)&As[(wr * (BM / 2) + m * 16 + lr) * 32 + lg * 8];
    #pragma unroll
    for (int n = 0; n < NR; ++n)
      bf[n] = *(const s16x8*)&Bs[(wc * (BN / 2) + n * 16 + lr) * 32 + lg * 8];
    #pragma unroll
    for (int m = 0; m < MR; ++m)
      #pragma unroll
      for (int n = 0; n < NR; ++n)
        acc[m][n] = __builtin_amdgcn_mfma_f32_16x16x32_bf16(af[m], bf[n], acc[m][n], 0, 0, 0);
    __syncthreads();
  }

  #pragma unroll
  for (int m = 0; m < MR; ++m) {
    #pragma unroll
    for (int n = 0; n < NR; ++n) {
      const int col = bn + wc * (BN / 2) + n * 16 + lr;
      const float bb = bias[col];
      #pragma unroll
      for (int r = 0; r < 4; ++r) {
        const int row = bm + wr * (BM / 2) + m * 16 + lg * 4 + r;
        float v = acc[m][n][r] + bb;
        if (ACT == 1) v = 0.5f * v * (1.0f + erff(v * 0.70710678118654752f));
        if (OUTF) Cf[(size_t)row * N + col] = v;
        else      Cb[(size_t)row * N + col] = f2bf(v);
      }
    }
  }
}

// ---------------------------------------------------------------------------
// MFMA flash attention v3 — ZERO barriers in the K-loop.
// All cross-wave LDS sharing removed: V comes pre-transposed from global VT
// ([B*H][64][S] bf16) so both K- and V-fragments are contiguous 16B global
// loads; P staging (Pb) is wave-private (lgkmcnt-ordered, no barrier).
// 2-deep prefetch of V-frags + bias survives across iterations because no
// __syncthreads -> no forced vmcnt(0) drain.
// ---------------------------------------------------------------------------
__global__ __launch_bounds__(256) void attn_mfma_kernel(
    const short* __restrict__ QKV, const short* __restrict__ VT,
    const float* __restrict__ bias, short* __restrict__ Ctx)
{
  __shared__ __align__(16) short Pb[4][16 * 72];  // per-wave P [q16][kv64]

  const int t = threadIdx.x;
  const int w = t >> 6, lane = t & 63;
  const int lr = lane & 15, lg = lane >> 4;
  const int qt = blockIdx.x, h = blockIdx.y, b = blockIdx.z;

  // Q A-fragments direct from global
  s16x8 aq0, aq1;
  {
    const size_t qoff = (size_t)(b * S_ + qt * 64 + w * 16 + lr) * QKV_P + h * 64;
    aq0 = *(const s16x8*)&QKV[qoff + lg * 8];
    aq1 = *(const s16x8*)&QKV[qoff + 32 + lg * 8];
  }

  f32x4 o[4];
  #pragma unroll
  for (int n = 0; n < 4; ++n) o[n] = (f32x4){0.f, 0.f, 0.f, 0.f};
  float mst[4] = {-1e30f, -1e30f, -1e30f, -1e30f};
  float lst[4] = {0.f, 0.f, 0.f, 0.f};

  const int vrow = (b * H_ + h) * 64;

  s16x8 bvA[4][2], bvB[4][2];
  float bbA[4][4], bbB[4][4];   // [r][n]

  // prefetch: V-fragments (contiguous from VT) + bias strip for tile kb
  auto loadVB = [&](s16x8 (&bv)[4][2], float (&bb)[4][4], int kb) {
    #pragma unroll
    for (int n = 0; n < 4; ++n) {
      const size_t vo = (size_t)(vrow + n * 16 + lr) * S_ + kb * 64 + lg * 8;
      bv[n][0] = *(const s16x8*)&VT[vo];
      bv[n][1] = *(const s16x8*)&VT[vo + 32];
    }
    #pragma unroll
    for (int r = 0; r < 4; ++r) {
      const size_t boff = (((size_t)(b * H_ + h)) * S_ + qt * 64 + w * 16 + lg * 4 + r) * S_
                        + kb * 64 + lr;
      #pragma unroll
      for (int n = 0; n < 4; ++n) bb[r][n] = bias[boff + n * 16];
    }
  };

  auto body = [&](s16x8 (&bv)[4][2], float (&bb)[4][4], int kb) {
    // K B-fragments (L2-resident; consumed immediately)
    s16x8 bk[4][2];
    #pragma unroll
    for (int n = 0; n < 4; ++n) {
      const size_t koff = (size_t)(b * S_ + kb * 64 + n * 16 + lr) * QKV_P + 512 + h * 64;
      bk[n][0] = *(const s16x8*)&QKV[koff + lg * 8];
      bk[n][1] = *(const s16x8*)&QKV[koff + 32 + lg * 8];
    }

    // S = Q K^T
    f32x4 c[4];
    #pragma unroll
    for (int n = 0; n < 4; ++n) c[n] = (f32x4){0.f, 0.f, 0.f, 0.f};
    #pragma unroll
    for (int n = 0; n < 4; ++n)
      c[n] = __builtin_amdgcn_mfma_f32_16x16x32_bf16(aq0, bk[n][0], c[n], 0, 0, 0);
    #pragma unroll
    for (int n = 0; n < 4; ++n)
      c[n] = __builtin_amdgcn_mfma_f32_16x16x32_bf16(aq1, bk[n][1], c[n], 0, 0, 0);

    // scale + bias (C layout: col=kv=n*16+lr, row=q=lg*4+r)
    float p[4][4];   // [n][r]
    #pragma unroll
    for (int r = 0; r < 4; ++r)
      #pragma unroll
      for (int n = 0; n < 4; ++n)
        p[n][r] = c[n][r] * 0.125f + bb[r][n];

    // online softmax per q-row (row = 16 lanes lr)
    #pragma unroll
    for (int r = 0; r < 4; ++r) {
      float rm = fmaxf(fmaxf(p[0][r], p[1][r]), fmaxf(p[2][r], p[3][r]));
      rm = fmaxf(rm, __shfl_xor(rm, 1));
      rm = fmaxf(rm, __shfl_xor(rm, 2));
      rm = fmaxf(rm, __shfl_xor(rm, 4));
      rm = fmaxf(rm, __shfl_xor(rm, 8));
      const float mnew = fmaxf(mst[r], rm);
      const float alpha = __expf(mst[r] - mnew);
      mst[r] = mnew;
      float rs = 0.f;
      #pragma unroll
      for (int n = 0; n < 4; ++n) { p[n][r] = __expf(p[n][r] - mnew); rs += p[n][r]; }
      rs += __shfl_xor(rs, 1);
      rs += __shfl_xor(rs, 2);
      rs += __shfl_xor(rs, 4);
      rs += __shfl_xor(rs, 8);
      lst[r] = lst[r] * alpha + rs;
      #pragma unroll
      for (int n = 0; n < 4; ++n) o[n][r] *= alpha;
      #pragma unroll
      for (int n = 0; n < 4; ++n)
        Pb[w][(lg * 4 + r) * 72 + n * 16 + lr] = f2bf(p[n][r]);
    }
    // wave-private LDS: compiler orders write->read via lgkmcnt, no barrier
    s16x8 pa0 = *(const s16x8*)&Pb[w][lr * 72 + lg * 8];
    s16x8 pa1 = *(const s16x8*)&Pb[w][lr * 72 + 32 + lg * 8];

    // PV: B-fragments from prefetched VT regs
    #pragma unroll
    for (int n = 0; n < 4; ++n)
      o[n] = __builtin_amdgcn_mfma_f32_16x16x32_bf16(pa0, bv[n][0], o[n], 0, 0, 0);
    #pragma unroll
    for (int n = 0; n < 4; ++n)
      o[n] = __builtin_amdgcn_mfma_f32_16x16x32_bf16(pa1, bv[n][1], o[n], 0, 0, 0);
  };

  loadVB(bvA, bbA, 0);
  for (int kb = 0; kb < S_ / 64; kb += 2) {
    loadVB(bvB, bbB, kb + 1);
    body(bvA, bbA, kb);
    if (kb + 2 < S_ / 64) loadVB(bvA, bbA, kb + 2);
    body(bvB, bbB, kb + 1);
  }

  #pragma unroll
  for (int r = 0; r < 4; ++r) {
    const int qrow = qt * 64 + w * 16 + lg * 4 + r;
    const float inv = 1.0f / lst[r];
    #pragma unroll
    for (int n = 0; n < 4; ++n)
      Ctx[(size_t)(b * S_ + qrow) * E_ + h * 64 + n * 16 + lr] = f2bf(o[n][r] * inv);
  }
}

// ---------------------------------------------------------------------------
// out = xin + LayerNorm(y)*g + beta ; optional bf16 copy.
// ---------------------------------------------------------------------------
__global__ __launch_bounds__(256) void add_ln_kernel(
    const float* __restrict__ xin, const float* __restrict__ y,
    const float* __restrict__ g, const float* __restrict__ beta,
    float* __restrict__ out, short* __restrict__ outb)
{
  const int row = blockIdx.x;
  const int tid = threadIdx.x;
  const size_t base = (size_t)row * E_;

  const float2 v = *(const float2*)&y[base + tid * 2];
  float sum = v.x + v.y;
  float sq  = v.x * v.x + v.y * v.y;
  #pragma unroll
  for (int m = 32; m >= 1; m >>= 1) {
    sum += __shfl_xor(sum, m);
    sq  += __shfl_xor(sq, m);
  }
  __shared__ float rs[4], rq[4];
  const int wid = tid >> 6, lane = tid & 63;
  if (lane == 0) { rs[wid] = sum; rq[wid] = sq; }
  __syncthreads();
  sum = rs[0] + rs[1] + rs[2] + rs[3];
  sq  = rq[0] + rq[1] + rq[2] + rq[3];

  const float mu   = sum * (1.0f / E_);
  const float var  = sq * (1.0f / E_) - mu * mu;
  const float rstd = rsqrtf(var + 1e-5f);

  const float2 xv = *(const float2*)&xin[base + tid * 2];
  const float2 gv = *(const float2*)&g[tid * 2];
  const float2 bv = *(const float2*)&beta[tid * 2];
  float2 ov;
  ov.x = xv.x + (v.x - mu) * rstd * gv.x + bv.x;
  ov.y = xv.y + (v.y - mu) * rstd * gv.y + bv.y;
  *(float2*)&out[base + tid * 2] = ov;
  if (outb) {
    outb[base + tid * 2]     = f2bf(ov.x);
    outb[base + tid * 2 + 1] = f2bf(ov.y);
  }
}

// ---------------------------------------------------------------------------
extern "C" void kernel_launch(void* const* d_in, const int* in_sizes, int n_in,
                              void* d_out, int out_size, void* d_ws, size_t ws_size,
                              hipStream_t stream)
{
  const float* x   = (const float*)d_in[0];
  const float* bia = (const float*)d_in[1];
  const float* Wq  = (const float*)d_in[2];
  const float* bq  = (const float*)d_in[3];
  const float* Wv  = (const float*)d_in[4];
  const float* bv  = (const float*)d_in[5];
  const float* Wo  = (const float*)d_in[6];
  const float* bo  = (const float*)d_in[7];
  const float* W1  = (const float*)d_in[8];
  const float* b1  = (const float*)d_in[9];
  const float* W2  = (const float*)d_in[10];
  const float* b2  = (const float*)d_in[11];
  const float* g1  = (const float*)d_in[12];
  const float* be1 = (const float*)d_in[13];
  const float* g2  = (const float*)d_in[14];
  const float* be2 = (const float*)d_in[15];
  float* out = (float*)d_out;
  char* ws = (char*)d_ws;

  const int NT = B_ * S_;                       // 4096
  const size_t MB = 1024 * 1024;

  short* xb   = (short*)(ws + 0 * MB);          // 4 MB
  short* qkvb = (short*)(ws + 4 * MB);          // 8 MB  [4096][1024]
  short* ctxb = (short*)(ws + 12 * MB);         // 4 MB
  short* h    = (short*)(ws + 16 * MB);         // 16 MB [4096][2048]
  short* WqvT = (short*)(ws + 32 * MB);         // 1 MB
  short* WoT  = (short*)(ws + 33 * MB);         // 0.5 MB
  short* W1T  = (short*)(ws + 34 * MB);         // 2 MB
  short* W2T  = (short*)(ws + 36 * MB);         // 2 MB
  float* bqv  = (float*)(ws + 38 * MB);         // 4 KB
  float* y    = (float*)(ws + 40 * MB);         // 8 MB
  float* x1   = (float*)(ws + 48 * MB);         // 8 MB
  short* x1b  = (short*)(ws + 56 * MB);         // 4 MB
  float* y2   = (float*)(ws + 60 * MB);         // 8 MB
  short* vt   = (short*)(ws + 68 * MB);         // 4 MB  [B*H][64][S]

  const dim3 blk(256);

  f2b_kernel<<<dim3((NT * E_) / 1024), blk, 0, stream>>>(x, xb, NT * E_);
  prep_weights_kernel<<<dim3(2817), blk, 0, stream>>>(
      Wq, Wv, Wo, W1, W2, bq, bv, WqvT, WoT, W1T, W2T, bqv);

  // qkv = x@[Wq|Wv] + [bq|bv]   (bf16, pitch 1024)
  gemm_t<128, 128, 0, 0><<<dim3(1024 / 128, NT / 128), blk, 0, stream>>>(
      xb, WqvT, bqv, nullptr, qkvb, NT, 1024, E_);

  // VT = head-wise transpose of kv
  vtrans_kernel<<<dim3(S_ / 32, 2, B_ * H_), blk, 0, stream>>>(qkvb, vt);

  // ctx = softmax(q kv^T / 8 + bias) @ kv
  attn_mfma_kernel<<<dim3(S_ / 64, H_, B_), blk, 0, stream>>>(qkvb, vt, bia, ctxb);

  // y = ctx@Wo + bo (fp32) ; x1 = x + LN(y)
  gemm_t<64, 64, 0, 1><<<dim3(E_ / 64, NT / 64), blk, 0, stream>>>(
      ctxb, WoT, bo, y, nullptr, NT, E_, E_);
  add_ln_kernel<<<dim3(NT), blk, 0, stream>>>(x, y, g1, be1, x1, x1b);

  // h = gelu(x1@W1 + b1) (bf16) ; y2 = h@W2 + b2 (fp32) ; out = x1 + LN(y2)
  gemm_t<128, 128, 1, 0><<<dim3(F_ / 128, NT / 128), blk, 0, stream>>>(
      x1b, W1T, b1, nullptr, h, NT, F_, E_);
  gemm_t<64, 64, 0, 1><<<dim3(E_ / 64, NT / 64), blk, 0, stream>>>(
      h, W2T, b2, y2, nullptr, NT, E_, F_);
  add_ln_kernel<<<dim3(NT), blk, 0, stream>>>(x1, y2, g2, be2, out, nullptr);
}